// Round 1
// 444.489 us; speedup vs baseline: 1.0114x; 1.0114x over previous
//
#include <hip/hip_runtime.h>
#include <hip/hip_bf16.h>

// Problem constants
#define B_    1024
#define NOBJ  128
#define RREL  32
#define DIM   512
#define MTOT  32768   // B_*RREL

typedef __bf16 bf16x8 __attribute__((ext_vector_type(8)));
typedef float  f32x4  __attribute__((ext_vector_type(4)));
typedef unsigned short us;

__device__ __forceinline__ us f2bf(float f) {
    unsigned int u = __float_as_uint(f);
    u += 0x7FFFu + ((u >> 16) & 1u);           // round-to-nearest-even
    return (us)(u >> 16);
}
__device__ __forceinline__ float bf2f(us h) {
    return __uint_as_float(((unsigned int)h) << 16);
}

__device__ __forceinline__ void load16_to_lds(const us* g, us* l) {
    // per-lane global address; LDS dest = wave-uniform base + lane*16
    __builtin_amdgcn_global_load_lds((const __attribute__((address_space(1))) void*)g,
                                     (__attribute__((address_space(3))) void*)l,
                                     16, 0, 0);
}

// ---------------------------------------------------------------------------
// Kernel 0: gather rows per relation, emit As=[s;o] bf16 (M x 1024) and
// Msum = bf16(s+o or s) (M x 512). 16B loads, 8B stores.
// ---------------------------------------------------------------------------
__global__ __launch_bounds__(256) void gather_kernel(
        const float* __restrict__ obj, const int* __restrict__ pairs,
        us* __restrict__ As, us* __restrict__ Msum) {
    int t = threadIdx.x;
    int g = t >> 7;          // which relation of the pair
    int c = t & 127;         // float4 chunk within 512-elem row
    int base = blockIdx.x * 8;
#pragma unroll
    for (int rr = 0; rr < 4; ++rr) {
        int m  = base + rr * 2 + g;
        int b  = m >> 5;
        int p0 = pairs[(m << 1) + 0];
        int p1 = pairs[(m << 1) + 1];
        const float4* srow = (const float4*)(obj + (size_t)(b * NOBJ + p0) * DIM);
        const float4* orow = (const float4*)(obj + (size_t)(b * NOBJ + p1) * DIM);
        float4 s4 = srow[c];
        float4 o4 = orow[c];
        size_t arow = (size_t)m * 1024;
        ushort4 sb = make_ushort4(f2bf(s4.x), f2bf(s4.y), f2bf(s4.z), f2bf(s4.w));
        ushort4 ob = make_ushort4(f2bf(o4.x), f2bf(o4.y), f2bf(o4.z), f2bf(o4.w));
        *(ushort4*)(As + arow + c * 4)       = sb;
        *(ushort4*)(As + arow + 512 + c * 4) = ob;
        float4 mz = s4;
        if (p0 != p1) { mz.x += o4.x; mz.y += o4.y; mz.z += o4.z; mz.w += o4.w; }
        *(ushort4*)(Msum + (size_t)m * 512 + c * 4) =
            make_ushort4(f2bf(mz.x), f2bf(mz.y), f2bf(mz.z), f2bf(mz.w));
    }
}

// ---------------------------------------------------------------------------
// Merged weight prep: 4 matrices f32 (K x N) -> bf16 (N x K) in one dispatch.
// 32x32 LDS tile; block id selects the matrix.
// ---------------------------------------------------------------------------
__global__ __launch_bounds__(256) void prep_weights(
        const float* __restrict__ fw, const float* __restrict__ gw,
        const float* __restrict__ w1, const float* __restrict__ w2,
        us* __restrict__ WfT, us* __restrict__ WgT,
        us* __restrict__ W1T, us* __restrict__ W2T) {
    __shared__ float t32[32][33];
    int id = blockIdx.x;
    const float* in; us* out; int K, N, local;
    if (id < 512)      { in = fw; out = WfT; K = 1024; N = 512; local = id; }
    else if (id < 768) { in = gw; out = WgT; K = 512;  N = 512; local = id - 512; }
    else if (id < 896) { in = w1; out = W1T; K = 512;  N = 256; local = id - 768; }
    else               { in = w2; out = W2T; K = 256;  N = 128; local = id - 896; }
    int tilesN = N >> 5;
    int bk = (local / tilesN) * 32;
    int bn = (local % tilesN) * 32;
    int t  = threadIdx.x;
    int tx = t & 31, ty = t >> 5;            // 32 x 8
#pragma unroll
    for (int i = 0; i < 4; ++i)
        t32[ty + i * 8][tx] = in[(size_t)(bk + ty + i * 8) * N + bn + tx];
    __syncthreads();
#pragma unroll
    for (int i = 0; i < 4; ++i)
        out[(size_t)(bn + ty + i * 8) * K + bk + tx] = f2bf(t32[tx][ty + i * 8]);
}

// ---------------------------------------------------------------------------
// Fused stages 1+2 (v2, single-accumulator):
//   rf = relu(Msum @ gcn_w + gcn_b) + (As @ fuse_w + fuse_b)   -> bf16 (M x 512)
// Key trick: relu is applied to the accumulator IN REGISTERS between the two
// K-phases (gcn K=512 first, then fuse K=1024 accumulates on top), so one
// acc set suffices -> tile 128 rows x FULL 512 cols, 8 waves (2x4), 512 thr.
// As/Msum each read exactly ONCE from HBM (was 4x). Double-buffered LDS,
// one barrier per K-step (T3-minimum pipeline): stage(next) -> ds_read(cur)
// -> 32 MFMA -> syncthreads.
// Per wave: 64x128 output = acc[4][8] f32x4 = 128 VGPR.
// ---------------------------------------------------------------------------
__global__ __launch_bounds__(512, 2) void gemm_fused12(
        const us* __restrict__ As,   // M x 1024
        const us* __restrict__ Msum, // M x 512
        const us* __restrict__ WfT,  // 512 x 1024 (N x K)
        const us* __restrict__ WgT,  // 512 x 512
        const float* __restrict__ fuse_b, const float* __restrict__ gcn_b,
        us* __restrict__ rf) {
    __shared__ __align__(16) us ldsA[2][4096];    // [buf][128 x 32]
    __shared__ __align__(16) us ldsB[2][16384];   // [buf][512 x 32]

    int tid  = threadIdx.x;
    int wid  = tid >> 6;
    int lane = tid & 63;
    int wm   = wid >> 2;      // 0..1 : row half (64 rows)
    int wn   = wid & 3;       // 0..3 : col quarter (128 cols)
    int m0   = blockIdx.x * 128;

    f32x4 acc[4][8];
#pragma unroll
    for (int i = 0; i < 4; ++i)
#pragma unroll
        for (int j = 0; j < 8; ++j)
#pragma unroll
            for (int k = 0; k < 4; ++k) acc[i][j][k] = 0.0f;

    int r = tid >> 2, c = tid & 3;        // staging role: row r, 16B chunk c
    const us* aG = Msum + (size_t)(m0 + r) * 512  + c * 8;
    const us* aF = As   + (size_t)(m0 + r) * 1024 + c * 8;

    int l15  = lane & 15;
    int koff = (lane >> 4) * 8;
    int aoff = (wm * 64  + l15) * 32 + koff;
    int boff = (wn * 128 + l15) * 32 + koff;

    float bg_[8], bf_[8];
#pragma unroll
    for (int j = 0; j < 8; ++j) {
        int col = wn * 128 + j * 16 + l15;
        bg_[j] = gcn_b[col];
        bf_[j] = fuse_b[col];
    }

    auto stageG = [&](int ks, int buf) {
        load16_to_lds(aG + ks * 32, &ldsA[buf][tid * 8]);
#pragma unroll
        for (int q = 0; q < 4; ++q)
            load16_to_lds(WgT + (size_t)(q * 128 + r) * 512 + ks * 32 + c * 8,
                          &ldsB[buf][q * 4096 + tid * 8]);
    };
    auto stageF = [&](int ks, int buf) {
        load16_to_lds(aF + ks * 32, &ldsA[buf][tid * 8]);
#pragma unroll
        for (int q = 0; q < 4; ++q)
            load16_to_lds(WfT + (size_t)(q * 128 + r) * 1024 + ks * 32 + c * 8,
                          &ldsB[buf][q * 4096 + tid * 8]);
    };
    auto compute = [&](int buf) {
        bf16x8 a[4], b[8];
#pragma unroll
        for (int i = 0; i < 4; ++i)
            a[i] = *(const bf16x8*)(&ldsA[buf][aoff + i * 512]);
#pragma unroll
        for (int j = 0; j < 8; ++j)
            b[j] = *(const bf16x8*)(&ldsB[buf][boff + j * 512]);
#pragma unroll
        for (int i = 0; i < 4; ++i)
#pragma unroll
            for (int j = 0; j < 8; ++j)
                acc[i][j] = __builtin_amdgcn_mfma_f32_16x16x32_bf16(a[i], b[j], acc[i][j], 0, 0, 0);
    };

    int cur = 0;
    stageG(0, 0);
    __syncthreads();

    // ---- phase G: gcn GEMM, K=512 (16 steps) ----
    for (int s = 0; s < 16; ++s) {
        if (s < 15) stageG(s + 1, cur ^ 1);
        else        stageF(0, cur ^ 1);       // pipeline across phase boundary
        compute(cur);
        if (s == 15) {
            // relu in-register: acc = max(acc + gcn_b, 0); fuse accumulates on top
#pragma unroll
            for (int i = 0; i < 4; ++i)
#pragma unroll
                for (int j = 0; j < 8; ++j)
#pragma unroll
                    for (int k = 0; k < 4; ++k)
                        acc[i][j][k] = fmaxf(acc[i][j][k] + bg_[j], 0.0f);
        }
        __syncthreads();
        cur ^= 1;
    }
    // ---- phase F: fuse GEMM, K=1024 (32 steps) ----
    for (int s = 0; s < 32; ++s) {
        if (s < 31) stageF(s + 1, cur ^ 1);
        compute(cur);
        __syncthreads();
        cur ^= 1;
    }

    // epilogue: C/D layout col = lane&15, row = (lane>>4)*4 + reg
    int crow = wm * 64 + (lane >> 4) * 4;
#pragma unroll
    for (int i = 0; i < 4; ++i)
#pragma unroll
        for (int j = 0; j < 8; ++j) {
            int col = wn * 128 + j * 16 + l15;
#pragma unroll
            for (int jj = 0; jj < 4; ++jj) {
                int row = m0 + crow + i * 16 + jj;
                rf[(size_t)row * 512 + col] = f2bf(acc[i][j][jj] + bf_[j]);
            }
        }
}

// ---------------------------------------------------------------------------
// Fused tail, 64-row blocks (512 blocks -> 2 blocks/CU):
//   h1 = relu(rf@W1+b1); h2 = relu(h1@W2+b2); out = softmax(h2@W3+b3)
// fc1: 4 waves across N=256 (64 cols each). fc2: 2x2 (N-half x K-half) with
// cross-wave f32 reduction through LDS. Head: 4 threads/row + shfl_xor.
// LDS overlay: H2 over stage region, red over dead H1. Total ~57.9 KB.
// ---------------------------------------------------------------------------
#define H1S 264   // shorts (132 floats) per row, pad 8
#define H2S 136
__global__ __launch_bounds__(256, 2) void tail_kernel(
        const us* __restrict__ rf,   // M x 512
        const us* __restrict__ W1T,  // 256 x 512 (N x K)
        const us* __restrict__ W2T,  // 128 x 256
        const float* __restrict__ b1, const float* __restrict__ b2,
        const float* __restrict__ w3, const float* __restrict__ b3,
        float* __restrict__ out) {
    __shared__ __align__(16) unsigned char pool[57888];
    us*    sA   = (us*)(pool);            //  4 KB: A stage 64x32
    us*    sB   = (us*)(pool + 4096);     // 16 KB: B stage (256x32 or 2x128x32)
    us*    sH2  = (us*)(pool);            // 17 KB overlay on stage (h2 64x136)
    us*    sH1  = (us*)(pool + 20480);    // 33.8 KB: h1 64x264
    float* sRed = (float*)(pool + 20480); // overlay: fc2 partials 64x132
    float* sW3  = (float*)(pool + 54272); // 3.5 KB
    float* sB3  = (float*)(pool + 57856);

    int tid  = threadIdx.x;
    int wid  = tid >> 6;
    int lane = tid & 63;
    int m0   = blockIdx.x * 64;

    for (int i = tid; i < 128 * 7; i += 256) sW3[i] = w3[i];
    if (tid < 7) sB3[tid] = b3[tid];

    int r = tid >> 2, c = tid & 3;        // staging role: row r (0..63), chunk c
    int koff = (lane >> 4) * 8;
    int l15  = lane & 15;

    // ================= fc1: C1[64x256] = rf[64x512] @ W1T^T =================
    f32x4 acc1[4][4];
#pragma unroll
    for (int i = 0; i < 4; ++i)
#pragma unroll
        for (int j = 0; j < 4; ++j)
#pragma unroll
            for (int k = 0; k < 4; ++k) acc1[i][j][k] = 0.0f;

    {
        const us* ag = rf + (size_t)(m0 + r) * 512 + c * 8;
        us* la = sA + wid * 512;
        for (int k0 = 0; k0 < 512; k0 += 32) {
            __syncthreads();
            load16_to_lds(ag + k0, la);
#pragma unroll
            for (int q = 0; q < 4; ++q)
                load16_to_lds(W1T + (size_t)(q * 64 + r) * 512 + k0 + c * 8,
                              sB + q * 2048 + wid * 512);
            __syncthreads();
            bf16x8 a[4], b[4];
#pragma unroll
            for (int i = 0; i < 4; ++i)
                a[i] = *(const bf16x8*)(sA + (l15 + i * 16) * 32 + koff);
#pragma unroll
            for (int j = 0; j < 4; ++j)
                b[j] = *(const bf16x8*)(sB + (wid * 64 + j * 16 + l15) * 32 + koff);
#pragma unroll
            for (int i = 0; i < 4; ++i)
#pragma unroll
                for (int j = 0; j < 4; ++j)
                    acc1[i][j] = __builtin_amdgcn_mfma_f32_16x16x32_bf16(a[i], b[j], acc1[i][j], 0, 0, 0);
        }
    }
    // epilogue fc1 -> sH1 (relu + bias); wave wid owns cols wid*64..+64
#pragma unroll
    for (int i = 0; i < 4; ++i)
#pragma unroll
        for (int j = 0; j < 4; ++j) {
            int col = wid * 64 + j * 16 + l15;
            float bb = b1[col];
#pragma unroll
            for (int jj = 0; jj < 4; ++jj) {
                int row = i * 16 + (lane >> 4) * 4 + jj;
                sH1[row * H1S + col] = f2bf(fmaxf(acc1[i][j][jj] + bb, 0.0f));
            }
        }

    // ================= fc2: C2[64x128] = H1[64x256] @ W2T^T =================
    // wave (kw = wid>>1, nw = wid&1): K-half kw, N-half nw (64 cols)
    int nw = wid & 1, kw = wid >> 1;
    f32x4 acc2[4][4];
#pragma unroll
    for (int i = 0; i < 4; ++i)
#pragma unroll
        for (int j = 0; j < 4; ++j)
#pragma unroll
            for (int k = 0; k < 4; ++k) acc2[i][j][k] = 0.0f;

    for (int t = 0; t < 4; ++t) {
        __syncthreads();     // also makes sH1 visible on t==0
#pragma unroll
        for (int s = 0; s < 2; ++s)
#pragma unroll
            for (int q = 0; q < 2; ++q)
                load16_to_lds(W2T + (size_t)(q * 64 + r) * 256 + s * 128 + t * 32 + c * 8,
                              sB + s * 4096 + q * 2048 + wid * 512);
        __syncthreads();
        bf16x8 a[4], b[4];
#pragma unroll
        for (int i = 0; i < 4; ++i)
            a[i] = *(const bf16x8*)(sH1 + (l15 + i * 16) * H1S + kw * 128 + t * 32 + koff);
#pragma unroll
        for (int j = 0; j < 4; ++j)
            b[j] = *(const bf16x8*)(sB + kw * 4096 + (nw * 64 + j * 16 + l15) * 32 + koff);
#pragma unroll
        for (int i = 0; i < 4; ++i)
#pragma unroll
            for (int j = 0; j < 4; ++j)
                acc2[i][j] = __builtin_amdgcn_mfma_f32_16x16x32_bf16(a[i], b[j], acc2[i][j], 0, 0, 0);
    }
    __syncthreads();                       // H1 reads done; red may overwrite
    if (kw == 1) {                         // write partials (overlay on H1)
#pragma unroll
        for (int i = 0; i < 4; ++i)
#pragma unroll
            for (int j = 0; j < 4; ++j) {
                int col = nw * 64 + j * 16 + l15;
#pragma unroll
                for (int jj = 0; jj < 4; ++jj) {
                    int row = i * 16 + (lane >> 4) * 4 + jj;
                    sRed[row * 132 + col] = acc2[i][j][jj];
                }
            }
    }
    __syncthreads();
    if (kw == 0) {                         // combine, relu, h2 -> sH2
#pragma unroll
        for (int i = 0; i < 4; ++i)
#pragma unroll
            for (int j = 0; j < 4; ++j) {
                int col = nw * 64 + j * 16 + l15;
                float bb = b2[col];
#pragma unroll
                for (int jj = 0; jj < 4; ++jj) {
                    int row = i * 16 + (lane >> 4) * 4 + jj;
                    float v = acc2[i][j][jj] + sRed[row * 132 + col] + bb;
                    sH2[row * H2S + col] = f2bf(fmaxf(v, 0.0f));
                }
            }
    }
    __syncthreads();

    // ================= head: 4 threads per row, shfl combine ================
    int row = tid >> 2;          // 0..63
    int p   = tid & 3;           // K quarter
    float accv[7];
#pragma unroll
    for (int cc = 0; cc < 7; ++cc) accv[cc] = 0.0f;
    const us* hrow = sH2 + row * H2S + p * 32;
    for (int kk = 0; kk < 8; ++kk) {
        ushort4 u = *(const ushort4*)(hrow + kk * 4);
        float f0 = bf2f(u.x), f1 = bf2f(u.y), f2 = bf2f(u.z), f3 = bf2f(u.w);
        int k = p * 32 + kk * 4;
#pragma unroll
        for (int cc = 0; cc < 7; ++cc) {
            accv[cc] = fmaf(f0, sW3[(k + 0) * 7 + cc], accv[cc]);
            accv[cc] = fmaf(f1, sW3[(k + 1) * 7 + cc], accv[cc]);
            accv[cc] = fmaf(f2, sW3[(k + 2) * 7 + cc], accv[cc]);
            accv[cc] = fmaf(f3, sW3[(k + 3) * 7 + cc], accv[cc]);
        }
    }
#pragma unroll
    for (int cc = 0; cc < 7; ++cc) {
        accv[cc] += __shfl_xor(accv[cc], 1);
        accv[cc] += __shfl_xor(accv[cc], 2);
    }
    if (p == 0) {
        float mx = accv[0] + sB3[0];
        float lg[7];
#pragma unroll
        for (int cc = 0; cc < 7; ++cc) { lg[cc] = accv[cc] + sB3[cc]; mx = fmaxf(mx, lg[cc]); }
        float sum = 0.f;
#pragma unroll
        for (int cc = 0; cc < 7; ++cc) { lg[cc] = __expf(lg[cc] - mx); sum += lg[cc]; }
        float inv = 1.0f / sum;
#pragma unroll
        for (int cc = 0; cc < 7; ++cc) out[(size_t)(m0 + row) * 7 + cc] = lg[cc] * inv;
    }
}

// ---------------------------------------------------------------------------
extern "C" void kernel_launch(void* const* d_in, const int* in_sizes, int n_in,
                              void* d_out, int out_size, void* d_ws, size_t ws_size,
                              hipStream_t stream) {
    (void)in_sizes; (void)n_in; (void)out_size; (void)ws_size;
    const float* obj    = (const float*)d_in[0];
    const int*   pairs  = (const int*)  d_in[1];
    const float* fuse_w = (const float*)d_in[2];
    const float* fuse_b = (const float*)d_in[3];
    const float* gcn_w  = (const float*)d_in[4];
    const float* gcn_b  = (const float*)d_in[5];
    const float* fc1_w  = (const float*)d_in[6];
    const float* fc1_b  = (const float*)d_in[7];
    const float* fc2_w  = (const float*)d_in[8];
    const float* fc2_b  = (const float*)d_in[9];
    const float* fc3_w  = (const float*)d_in[10];
    const float* fc3_b  = (const float*)d_in[11];
    float* out = (float*)d_out;

    char* ws = (char*)d_ws;
    us* As   = (us*)(ws);                    // 64 MB
    us* Msum = (us*)(ws + (64u  << 20));     // 32 MB
    us* rf   = (us*)(ws + (96u  << 20));     // 32 MB
    us* WfT  = (us*)(ws + (128u << 20));     //  1 MB
    us* WgT  = (us*)(ws + (129u << 20));     // 512 KB
    us* W1T  = (us*)(ws + (130u << 20));     // 256 KB
    us* W2T  = (us*)(ws + (131u << 20));     //  64 KB

    // Stage 0: gather + merged weight transposes (f32 KxN -> bf16 NxK)
    gather_kernel<<<MTOT / 8, 256, 0, stream>>>(obj, pairs, As, Msum);
    prep_weights<<<928, 256, 0, stream>>>(fuse_w, gcn_w, fc1_w, fc2_w,
                                          WfT, WgT, W1T, W2T);

    // Stage 1+2 fused (v2): rf = relu(Msum@gcn_w+gcn_b) + As@fuse_w+fuse_b
    // single-acc relu-reorder, 128x512 tile, 256 blocks (1/CU), 512 threads
    gemm_fused12<<<MTOT / 128, 512, 0, stream>>>(
        As, Msum, WfT, WgT, fuse_b, gcn_b, rf);

    // Stage 3+4+5 fused: out = softmax(relu(relu(rf@W1+b1)@W2+b2)@W3+b3)
    tail_kernel<<<MTOT / 64, 256, 0, stream>>>(
        rf, W1T, W2T, fc1_b, fc2_b, fc3_w, fc3_b, out);
}

// Round 2
// 425.779 us; speedup vs baseline: 1.0558x; 1.0439x over previous
//
#include <hip/hip_runtime.h>
#include <hip/hip_bf16.h>

// Problem constants
#define B_    1024
#define NOBJ  128
#define RREL  32
#define DIM   512
#define MTOT  32768   // B_*RREL

typedef __bf16 bf16x8 __attribute__((ext_vector_type(8)));
typedef float  f32x4  __attribute__((ext_vector_type(4)));
typedef unsigned short us;
typedef unsigned short us8v __attribute__((ext_vector_type(8)));

__device__ __forceinline__ us f2bf(float f) {
    unsigned int u = __float_as_uint(f);
    u += 0x7FFFu + ((u >> 16) & 1u);           // round-to-nearest-even
    return (us)(u >> 16);
}
__device__ __forceinline__ float bf2f(us h) {
    return __uint_as_float(((unsigned int)h) << 16);
}

__device__ __forceinline__ void load16_to_lds(const us* g, us* l) {
    // per-lane global address; LDS dest = wave-uniform base + lane*16
    __builtin_amdgcn_global_load_lds((const __attribute__((address_space(1))) void*)g,
                                     (__attribute__((address_space(3))) void*)l,
                                     16, 0, 0);
}

// ---------------------------------------------------------------------------
// Merged weight prep: 4 matrices f32 (K x N) -> bf16 (N x K) in one dispatch.
// 32x32 LDS tile; block id selects the matrix.
// ---------------------------------------------------------------------------
__global__ __launch_bounds__(256) void prep_weights(
        const float* __restrict__ fw, const float* __restrict__ gw,
        const float* __restrict__ w1, const float* __restrict__ w2,
        us* __restrict__ WfT, us* __restrict__ WgT,
        us* __restrict__ W1T, us* __restrict__ W2T) {
    __shared__ float t32[32][33];
    int id = blockIdx.x;
    const float* in; us* out; int K, N, local;
    if (id < 512)      { in = fw; out = WfT; K = 1024; N = 512; local = id; }
    else if (id < 768) { in = gw; out = WgT; K = 512;  N = 512; local = id - 512; }
    else if (id < 896) { in = w1; out = W1T; K = 512;  N = 256; local = id - 768; }
    else               { in = w2; out = W2T; K = 256;  N = 128; local = id - 896; }
    int tilesN = N >> 5;
    int bk = (local / tilesN) * 32;
    int bn = (local % tilesN) * 32;
    int t  = threadIdx.x;
    int tx = t & 31, ty = t >> 5;            // 32 x 8
#pragma unroll
    for (int i = 0; i < 4; ++i)
        t32[ty + i * 8][tx] = in[(size_t)(bk + ty + i * 8) * N + bn + tx];
    __syncthreads();
#pragma unroll
    for (int i = 0; i < 4; ++i)
        out[(size_t)(bn + ty + i * 8) * K + bk + tx] = f2bf(t32[tx][ty + i * 8]);
}

// ---------------------------------------------------------------------------
// Fused stages 0+1+2 (v3): gather fused into the GEMM's A-staging.
//   rf = relu(Msum @ gcn_w + gcn_b) + ([s;o] @ fuse_w + fuse_b)  -> bf16 M x 512
// Msum = s + (p0!=p1)*o, gathered on the fly from obj_feats (f32), converted
// to bf16 in-register, ds_write_b128 into the SAME linear LDS layout the old
// global_load_lds produced (fragment reads / MFMA code untouched).
// 48 K-steps: 16 G-steps (K=512), relu-in-register, 32 F-steps (K=1024).
// T14 split: f32 A-loads for tile t+1 issue BEFORE tile t's MFMAs; cvt +
// ds_write land after. B tiles (bf16 weights) stay on global_load_lds.
// 8 waves (2x4), per wave 64x128 output = acc[4][8] = 128 VGPR.
// ---------------------------------------------------------------------------
__global__ __launch_bounds__(512, 2) void gemm_fused12(
        const float* __restrict__ obj,   // B x NOBJ x 512 f32
        const int*   __restrict__ pairs, // M x 2
        const us* __restrict__ WfT,      // 512 x 1024 (N x K) bf16
        const us* __restrict__ WgT,      // 512 x 512
        const float* __restrict__ fuse_b, const float* __restrict__ gcn_b,
        us* __restrict__ rf) {
    __shared__ __align__(16) us ldsA[2][4096];    // [buf][128 x 32]
    __shared__ __align__(16) us ldsB[2][16384];   // [buf][512 x 32]

    int tid  = threadIdx.x;
    int wid  = tid >> 6;
    int lane = tid & 63;
    int wm   = wid >> 2;      // 0..1 : row half (64 rows)
    int wn   = wid & 3;       // 0..3 : col quarter (128 cols)
    int m0   = blockIdx.x * 128;

    f32x4 acc[4][8];
#pragma unroll
    for (int i = 0; i < 4; ++i)
#pragma unroll
        for (int j = 0; j < 8; ++j)
#pragma unroll
            for (int k = 0; k < 4; ++k) acc[i][j][k] = 0.0f;

    int r = tid >> 2, c = tid & 3;        // staging role: row r (0..127), chunk c (8 floats)
    int m  = m0 + r;
    int p0 = pairs[2 * m + 0];
    int p1 = pairs[2 * m + 1];
    int bi = m >> 5;                      // batch (32 relations per batch)
    const float* sP = obj + (size_t)(bi * NOBJ + p0) * DIM + c * 8;
    const float* oP = obj + (size_t)(bi * NOBJ + p1) * DIM + c * 8;
    float osc = (p0 != p1) ? 1.0f : 0.0f; // Msum = s (+ o unless self-pair)

    int l15  = lane & 15;
    int koff = (lane >> 4) * 8;
    int aoff = (wm * 64  + l15) * 32 + koff;
    int boff = (wn * 128 + l15) * 32 + koff;

    float bg_[8], bf_[8];
#pragma unroll
    for (int j = 0; j < 8; ++j) {
        int col = wn * 128 + j * 16 + l15;
        bg_[j] = gcn_b[col];
        bf_[j] = fuse_b[col];
    }

    us* aDst0 = &ldsA[0][r * 32 + c * 8];
    us* aDst1 = &ldsA[1][r * 32 + c * 8];

    auto compute = [&](int buf) {
        bf16x8 a[4], b[8];
#pragma unroll
        for (int i = 0; i < 4; ++i)
            a[i] = *(const bf16x8*)(&ldsA[buf][aoff + i * 512]);
#pragma unroll
        for (int j = 0; j < 8; ++j)
            b[j] = *(const bf16x8*)(&ldsB[buf][boff + j * 512]);
#pragma unroll
        for (int i = 0; i < 4; ++i)
#pragma unroll
            for (int j = 0; j < 8; ++j)
                acc[i][j] = __builtin_amdgcn_mfma_f32_16x16x32_bf16(a[i], b[j], acc[i][j], 0, 0, 0);
    };

    // ---- prologue: stage tile 0 (G-phase, k0 = 0) into buf 0 ----
    {
        float4 sa = *(const float4*)(sP);
        float4 sb = *(const float4*)(sP + 4);
        float4 oa = *(const float4*)(oP);
        float4 ob = *(const float4*)(oP + 4);
        us8v u;
        u[0] = f2bf(fmaf(osc, oa.x, sa.x)); u[1] = f2bf(fmaf(osc, oa.y, sa.y));
        u[2] = f2bf(fmaf(osc, oa.z, sa.z)); u[3] = f2bf(fmaf(osc, oa.w, sa.w));
        u[4] = f2bf(fmaf(osc, ob.x, sb.x)); u[5] = f2bf(fmaf(osc, ob.y, sb.y));
        u[6] = f2bf(fmaf(osc, ob.z, sb.z)); u[7] = f2bf(fmaf(osc, ob.w, sb.w));
        *(us8v*)aDst0 = u;
#pragma unroll
        for (int q = 0; q < 4; ++q)
            load16_to_lds(WgT + (size_t)(q * 128 + r) * 512 + c * 8,
                          &ldsB[0][q * 4096 + tid * 8]);
    }
    __syncthreads();

    // ---- unified K-loop: t = 0..15 G-phase (K=512), t = 16..47 F-phase (K=1024)
    int cur = 0;
    for (int t = 0; t < 48; ++t) {
        float4 ra, rb, rc, rd;
        int  nt = t + 1;
        bool hv = nt < 48;
        bool gm = nt < 16;
        if (hv) {
            if (gm) {
                int k0 = nt * 32;
                ra = *(const float4*)(sP + k0);
                rb = *(const float4*)(sP + k0 + 4);
                rc = *(const float4*)(oP + k0);
                rd = *(const float4*)(oP + k0 + 4);
#pragma unroll
                for (int q = 0; q < 4; ++q)
                    load16_to_lds(WgT + (size_t)(q * 128 + r) * 512 + k0 + c * 8,
                                  &ldsB[cur ^ 1][q * 4096 + tid * 8]);
            } else {
                int kf = (nt - 16) * 32;
                const float* p = (kf < 512) ? (sP + kf) : (oP + (kf - 512));
                ra = *(const float4*)(p);
                rb = *(const float4*)(p + 4);
#pragma unroll
                for (int q = 0; q < 4; ++q)
                    load16_to_lds(WfT + (size_t)(q * 128 + r) * 1024 + kf + c * 8,
                                  &ldsB[cur ^ 1][q * 4096 + tid * 8]);
            }
        }

        compute(cur);

        if (t == 15) {
            // G complete: relu in-register; F accumulates on top
#pragma unroll
            for (int i = 0; i < 4; ++i)
#pragma unroll
                for (int j = 0; j < 8; ++j)
#pragma unroll
                    for (int k = 0; k < 4; ++k)
                        acc[i][j][k] = fmaxf(acc[i][j][k] + bg_[j], 0.0f);
        }

        if (hv) {
            us8v u;
            if (gm) {
                u[0] = f2bf(fmaf(osc, rc.x, ra.x)); u[1] = f2bf(fmaf(osc, rc.y, ra.y));
                u[2] = f2bf(fmaf(osc, rc.z, ra.z)); u[3] = f2bf(fmaf(osc, rc.w, ra.w));
                u[4] = f2bf(fmaf(osc, rd.x, rb.x)); u[5] = f2bf(fmaf(osc, rd.y, rb.y));
                u[6] = f2bf(fmaf(osc, rd.z, rb.z)); u[7] = f2bf(fmaf(osc, rd.w, rb.w));
            } else {
                u[0] = f2bf(ra.x); u[1] = f2bf(ra.y); u[2] = f2bf(ra.z); u[3] = f2bf(ra.w);
                u[4] = f2bf(rb.x); u[5] = f2bf(rb.y); u[6] = f2bf(rb.z); u[7] = f2bf(rb.w);
            }
            *(us8v*)((cur == 0) ? aDst1 : aDst0) = u;
        }
        __syncthreads();
        cur ^= 1;
    }

    // epilogue: C/D layout col = lane&15, row = (lane>>4)*4 + reg
    int crow = wm * 64 + (lane >> 4) * 4;
#pragma unroll
    for (int i = 0; i < 4; ++i)
#pragma unroll
        for (int j = 0; j < 8; ++j) {
            int col = wn * 128 + j * 16 + l15;
#pragma unroll
            for (int jj = 0; jj < 4; ++jj) {
                int row = m0 + crow + i * 16 + jj;
                rf[(size_t)row * 512 + col] = f2bf(acc[i][j][jj] + bf_[j]);
            }
        }
}

// ---------------------------------------------------------------------------
// Fused tail, 64-row blocks (512 blocks -> 2 blocks/CU):
//   h1 = relu(rf@W1+b1); h2 = relu(h1@W2+b2); out = softmax(h2@W3+b3)
// fc1: 4 waves across N=256 (64 cols each). fc2: 2x2 (N-half x K-half) with
// cross-wave f32 reduction through LDS. Head: 4 threads/row + shfl_xor.
// LDS overlay: H2 over stage region, red over dead H1. Total ~57.9 KB.
// ---------------------------------------------------------------------------
#define H1S 264   // shorts (132 floats) per row, pad 8
#define H2S 136
__global__ __launch_bounds__(256, 2) void tail_kernel(
        const us* __restrict__ rf,   // M x 512
        const us* __restrict__ W1T,  // 256 x 512 (N x K)
        const us* __restrict__ W2T,  // 128 x 256
        const float* __restrict__ b1, const float* __restrict__ b2,
        const float* __restrict__ w3, const float* __restrict__ b3,
        float* __restrict__ out) {
    __shared__ __align__(16) unsigned char pool[57888];
    us*    sA   = (us*)(pool);            //  4 KB: A stage 64x32
    us*    sB   = (us*)(pool + 4096);     // 16 KB: B stage (256x32 or 2x128x32)
    us*    sH2  = (us*)(pool);            // 17 KB overlay on stage (h2 64x136)
    us*    sH1  = (us*)(pool + 20480);    // 33.8 KB: h1 64x264
    float* sRed = (float*)(pool + 20480); // overlay: fc2 partials 64x132
    float* sW3  = (float*)(pool + 54272); // 3.5 KB
    float* sB3  = (float*)(pool + 57856);

    int tid  = threadIdx.x;
    int wid  = tid >> 6;
    int lane = tid & 63;
    int m0   = blockIdx.x * 64;

    for (int i = tid; i < 128 * 7; i += 256) sW3[i] = w3[i];
    if (tid < 7) sB3[tid] = b3[tid];

    int r = tid >> 2, c = tid & 3;        // staging role: row r (0..63), chunk c
    int koff = (lane >> 4) * 8;
    int l15  = lane & 15;

    // ================= fc1: C1[64x256] = rf[64x512] @ W1T^T =================
    f32x4 acc1[4][4];
#pragma unroll
    for (int i = 0; i < 4; ++i)
#pragma unroll
        for (int j = 0; j < 4; ++j)
#pragma unroll
            for (int k = 0; k < 4; ++k) acc1[i][j][k] = 0.0f;

    {
        const us* ag = rf + (size_t)(m0 + r) * 512 + c * 8;
        us* la = sA + wid * 512;
        for (int k0 = 0; k0 < 512; k0 += 32) {
            __syncthreads();
            load16_to_lds(ag + k0, la);
#pragma unroll
            for (int q = 0; q < 4; ++q)
                load16_to_lds(W1T + (size_t)(q * 64 + r) * 512 + k0 + c * 8,
                              sB + q * 2048 + wid * 512);
            __syncthreads();
            bf16x8 a[4], b[4];
#pragma unroll
            for (int i = 0; i < 4; ++i)
                a[i] = *(const bf16x8*)(sA + (l15 + i * 16) * 32 + koff);
#pragma unroll
            for (int j = 0; j < 4; ++j)
                b[j] = *(const bf16x8*)(sB + (wid * 64 + j * 16 + l15) * 32 + koff);
#pragma unroll
            for (int i = 0; i < 4; ++i)
#pragma unroll
                for (int j = 0; j < 4; ++j)
                    acc1[i][j] = __builtin_amdgcn_mfma_f32_16x16x32_bf16(a[i], b[j], acc1[i][j], 0, 0, 0);
        }
    }
    // epilogue fc1 -> sH1 (relu + bias); wave wid owns cols wid*64..+64
#pragma unroll
    for (int i = 0; i < 4; ++i)
#pragma unroll
        for (int j = 0; j < 4; ++j) {
            int col = wid * 64 + j * 16 + l15;
            float bb = b1[col];
#pragma unroll
            for (int jj = 0; jj < 4; ++jj) {
                int row = i * 16 + (lane >> 4) * 4 + jj;
                sH1[row * H1S + col] = f2bf(fmaxf(acc1[i][j][jj] + bb, 0.0f));
            }
        }

    // ================= fc2: C2[64x128] = H1[64x256] @ W2T^T =================
    // wave (kw = wid>>1, nw = wid&1): K-half kw, N-half nw (64 cols)
    int nw = wid & 1, kw = wid >> 1;
    f32x4 acc2[4][4];
#pragma unroll
    for (int i = 0; i < 4; ++i)
#pragma unroll
        for (int j = 0; j < 4; ++j)
#pragma unroll
            for (int k = 0; k < 4; ++k) acc2[i][j][k] = 0.0f;

    for (int t = 0; t < 4; ++t) {
        __syncthreads();     // also makes sH1 visible on t==0
#pragma unroll
        for (int s = 0; s < 2; ++s)
#pragma unroll
            for (int q = 0; q < 2; ++q)
                load16_to_lds(W2T + (size_t)(q * 64 + r) * 256 + s * 128 + t * 32 + c * 8,
                              sB + s * 4096 + q * 2048 + wid * 512);
        __syncthreads();
        bf16x8 a[4], b[4];
#pragma unroll
        for (int i = 0; i < 4; ++i)
            a[i] = *(const bf16x8*)(sH1 + (l15 + i * 16) * H1S + kw * 128 + t * 32 + koff);
#pragma unroll
        for (int j = 0; j < 4; ++j)
            b[j] = *(const bf16x8*)(sB + kw * 4096 + (nw * 64 + j * 16 + l15) * 32 + koff);
#pragma unroll
        for (int i = 0; i < 4; ++i)
#pragma unroll
            for (int j = 0; j < 4; ++j)
                acc2[i][j] = __builtin_amdgcn_mfma_f32_16x16x32_bf16(a[i], b[j], acc2[i][j], 0, 0, 0);
    }
    __syncthreads();                       // H1 reads done; red may overwrite
    if (kw == 1) {                         // write partials (overlay on H1)
#pragma unroll
        for (int i = 0; i < 4; ++i)
#pragma unroll
            for (int j = 0; j < 4; ++j) {
                int col = nw * 64 + j * 16 + l15;
#pragma unroll
                for (int jj = 0; jj < 4; ++jj) {
                    int row = i * 16 + (lane >> 4) * 4 + jj;
                    sRed[row * 132 + col] = acc2[i][j][jj];
                }
            }
    }
    __syncthreads();
    if (kw == 0) {                         // combine, relu, h2 -> sH2
#pragma unroll
        for (int i = 0; i < 4; ++i)
#pragma unroll
            for (int j = 0; j < 4; ++j) {
                int col = nw * 64 + j * 16 + l15;
                float bb = b2[col];
#pragma unroll
                for (int jj = 0; jj < 4; ++jj) {
                    int row = i * 16 + (lane >> 4) * 4 + jj;
                    float v = acc2[i][j][jj] + sRed[row * 132 + col] + bb;
                    sH2[row * H2S + col] = f2bf(fmaxf(v, 0.0f));
                }
            }
    }
    __syncthreads();

    // ================= head: 4 threads per row, shfl combine ================
    int row = tid >> 2;          // 0..63
    int p   = tid & 3;           // K quarter
    float accv[7];
#pragma unroll
    for (int cc = 0; cc < 7; ++cc) accv[cc] = 0.0f;
    const us* hrow = sH2 + row * H2S + p * 32;
    for (int kk = 0; kk < 8; ++kk) {
        ushort4 u = *(const ushort4*)(hrow + kk * 4);
        float f0 = bf2f(u.x), f1 = bf2f(u.y), f2 = bf2f(u.z), f3 = bf2f(u.w);
        int k = p * 32 + kk * 4;
#pragma unroll
        for (int cc = 0; cc < 7; ++cc) {
            accv[cc] = fmaf(f0, sW3[(k + 0) * 7 + cc], accv[cc]);
            accv[cc] = fmaf(f1, sW3[(k + 1) * 7 + cc], accv[cc]);
            accv[cc] = fmaf(f2, sW3[(k + 2) * 7 + cc], accv[cc]);
            accv[cc] = fmaf(f3, sW3[(k + 3) * 7 + cc], accv[cc]);
        }
    }
#pragma unroll
    for (int cc = 0; cc < 7; ++cc) {
        accv[cc] += __shfl_xor(accv[cc], 1);
        accv[cc] += __shfl_xor(accv[cc], 2);
    }
    if (p == 0) {
        float mx = accv[0] + sB3[0];
        float lg[7];
#pragma unroll
        for (int cc = 0; cc < 7; ++cc) { lg[cc] = accv[cc] + sB3[cc]; mx = fmaxf(mx, lg[cc]); }
        float sum = 0.f;
#pragma unroll
        for (int cc = 0; cc < 7; ++cc) { lg[cc] = __expf(lg[cc] - mx); sum += lg[cc]; }
        float inv = 1.0f / sum;
#pragma unroll
        for (int cc = 0; cc < 7; ++cc) out[(size_t)(m0 + row) * 7 + cc] = lg[cc] * inv;
    }
}

// ---------------------------------------------------------------------------
extern "C" void kernel_launch(void* const* d_in, const int* in_sizes, int n_in,
                              void* d_out, int out_size, void* d_ws, size_t ws_size,
                              hipStream_t stream) {
    (void)in_sizes; (void)n_in; (void)out_size; (void)ws_size;
    const float* obj    = (const float*)d_in[0];
    const int*   pairs  = (const int*)  d_in[1];
    const float* fuse_w = (const float*)d_in[2];
    const float* fuse_b = (const float*)d_in[3];
    const float* gcn_w  = (const float*)d_in[4];
    const float* gcn_b  = (const float*)d_in[5];
    const float* fc1_w  = (const float*)d_in[6];
    const float* fc1_b  = (const float*)d_in[7];
    const float* fc2_w  = (const float*)d_in[8];
    const float* fc2_b  = (const float*)d_in[9];
    const float* fc3_w  = (const float*)d_in[10];
    const float* fc3_b  = (const float*)d_in[11];
    float* out = (float*)d_out;

    char* ws = (char*)d_ws;
    us* rf   = (us*)(ws);                    // 32 MB
    us* WfT  = (us*)(ws + (32u << 20));      //  1 MB
    us* WgT  = (us*)(ws + (33u << 20));      // 512 KB
    us* W1T  = (us*)(ws + (34u << 20));      // 256 KB
    us* W2T  = (us*)(ws + (35u << 20));      //  64 KB

    // Stage 0: merged weight transposes (f32 KxN -> bf16 NxK)
    prep_weights<<<928, 256, 0, stream>>>(fuse_w, gcn_w, fc1_w, fc2_w,
                                          WfT, WgT, W1T, W2T);

    // Stage 0+1+2 fused (v3): gather-on-the-fly + rf = relu(G)+F
    gemm_fused12<<<MTOT / 128, 512, 0, stream>>>(
        obj, pairs, WfT, WgT, fuse_b, gcn_b, rf);

    // Stage 3+4+5 fused: out = softmax(relu(relu(rf@W1+b1)@W2+b2)@W3+b3)
    tail_kernel<<<MTOT / 64, 256, 0, stream>>>(
        rf, W1T, W2T, fc1_b, fc2_b, fc3_w, fc3_b, out);
}